// Round 7
// baseline (240.136 us; speedup 1.0000x reference)
//
#include <hip/hip_runtime.h>
#include <math.h>

#define B_ 64
#define F_ 32
#define S_ 512
#define P_ 96
#define E_ 8
#define H_ 2048
#define M_ 2048   // B_*F_ rows, m = b*F_ + f

// ---- k_experts tiling: 512 threads, 128m x 128h tiles, BK=64, fp8 GEMM1 ----
#define BM 128
#define BH 128
#define BK 64
#define ZSPLIT 4
#define HPZ (H_ / ZSPLIT)   // 512 h per z-block
#define NHT (HPZ / BH)      // 4 h-chunks per block
#define NKC (S_ / BK)       // 8 k-chunks
#define HPITCH 136          // 128 + 8 skew (bf16)
#define W1SCALE 8.0f        // pre-scale W1 into e4m3 normal range; /8 in epilogue

typedef __bf16 bf16x8 __attribute__((ext_vector_type(8)));
typedef __bf16 bf16x4 __attribute__((ext_vector_type(4)));
typedef float f32x4 __attribute__((ext_vector_type(4)));
typedef unsigned char u8;
typedef int i32x2 __attribute__((ext_vector_type(2)));

#define MFMA16(a, b, c) __builtin_amdgcn_mfma_f32_16x16x32_bf16((a), (b), (c), 0, 0, 0)
#define MFMA8(a, b, c) __builtin_amdgcn_mfma_f32_16x16x32_fp8_fp8((a), (b), (c), 0, 0, 0)

// async global->LDS, 16B per lane; LDS dest is wave-uniform base + lane*16
#define GLL16(gp, lp) __builtin_amdgcn_global_load_lds(                     \
    (const __attribute__((address_space(1))) void*)(gp),                    \
    (__attribute__((address_space(3))) void*)(lp), 16, 0, 0)

// pack 4 f32 -> 4 fp8 e4m3 (OCP, RNE-saturate) into an int
__device__ __forceinline__ int pk_fp8x4(float a, float b, float c, float d) {
  int v = __builtin_amdgcn_cvt_pk_fp8_f32(a, b, 0, false);
  return __builtin_amdgcn_cvt_pk_fp8_f32(c, d, v, true);
}

// sigmoid-approx gelu: x * sigmoid(1.702 x)
__device__ __forceinline__ float fast_gelu(float x) {
  float e = __builtin_amdgcn_exp2f(-2.45546696f * x);
  return x * __builtin_amdgcn_rcpf(1.0f + e);
}

// =================== k_prep_w1 (256 threads, 256 blocks): W1 -> fp8 transpose ===================
// (e, 64-h strip) x all 512 s: [E][S][H] f32 -> w1q [E][H][S] fp8 (x W1SCALE)
__global__ __launch_bounds__(256) void k_prep_w1(const float* __restrict__ W1,
                                                 u8* __restrict__ w1q) {
  __shared__ __align__(16) __bf16 btile[256 * 68];   // 34,816 B
  const int tid = threadIdx.x;
  int e = blockIdx.x >> 5, hstrip = blockIdx.x & 31;
  const float* src = W1 + (size_t)e * S_ * H_ + hstrip * 64;
  u8* dstb = w1q + (size_t)e * H_ * S_ + (size_t)(hstrip * 64) * S_;
#pragma unroll
  for (int pass = 0; pass < 2; ++pass) {
    {
      int rb = tid >> 2;
      int hseg = (tid & 3) * 16;
#pragma unroll
      for (int it = 0; it < 4; ++it) {
        int r = it * 64 + rb;
        const float* srow = src + (size_t)(pass * 256 + r) * H_ + hseg;
#pragma unroll
        for (int k = 0; k < 4; ++k) {
          f32x4 v = *(const f32x4*)(srow + k * 4);
          bf16x4 o = {(__bf16)v[0], (__bf16)v[1], (__bf16)v[2], (__bf16)v[3]};
          *(bf16x4*)&btile[r * 68 + hseg + k * 4] = o;
        }
      }
    }
    __syncthreads();
    {
      int h = tid >> 2;
      int sseg = (tid & 3) * 64;
      u8* drow = dstb + (size_t)h * S_ + pass * 256 + sseg;
#pragma unroll
      for (int g = 0; g < 8; ++g) {
        float v[8];
#pragma unroll
        for (int j = 0; j < 8; ++j)
          v[j] = W1SCALE * (float)btile[(sseg + g * 8 + j) * 68 + h];
        i32x2 o = {pk_fp8x4(v[0], v[1], v[2], v[3]), pk_fp8x4(v[4], v[5], v[6], v[7])};
        *(i32x2*)(drow + g * 8) = o;
      }
    }
    __syncthreads();
  }
}

// =================== k_prep_rest (256 threads, 1536 blocks) ===================
// blocks [0,512):     W2 [E][H][P] f32 -> w2t [E][P][H] bf16 (64h x 48p tiles)
// blocks [512,1024):  x convert f32 -> fp8 (8 elems/thread)
// blocks [1024,1536): gates (4 rows per block)
__global__ __launch_bounds__(256) void k_prep_rest(const float* __restrict__ x,
                                                   const float* __restrict__ te,
                                                   const float* __restrict__ Wg,
                                                   const float* __restrict__ bg,
                                                   const float* __restrict__ W2,
                                                   u8* __restrict__ xq,
                                                   __bf16* __restrict__ w2t,
                                                   float* __restrict__ gates) {
  __shared__ float tile[64 * 49];
  const int blk = blockIdx.x;
  const int tid = threadIdx.x;

  if (blk < 512) {                        // ---- W2 transpose: tile 64h x 48p
    int e = blk >> 6, hi = (blk >> 1) & 31, ph = blk & 1;
    const float* src = W2 + (size_t)e * H_ * P_ + (size_t)(hi * 64) * P_ + ph * 48;
    {
      int h = tid & 63;
      int seg = tid >> 6;
#pragma unroll
      for (int k = 0; k < 3; ++k) {
        f32x4 v = *(const f32x4*)(src + (size_t)h * P_ + seg * 12 + k * 4);
#pragma unroll
        for (int u = 0; u < 4; ++u) tile[h * 49 + seg * 12 + k * 4 + u] = v[u];
      }
    }
    __syncthreads();
    if (tid < 192) {
      int p = tid >> 2;
      int hb = (tid & 3) * 16;
      __bf16* dst = w2t + (size_t)e * P_ * H_ + (size_t)(ph * 48 + p) * H_ + hi * 64 + hb;
      bf16x8 o0, o1;
#pragma unroll
      for (int k = 0; k < 8; ++k) o0[k] = (__bf16)tile[(hb + k) * 49 + p];
#pragma unroll
      for (int k = 0; k < 8; ++k) o1[k] = (__bf16)tile[(hb + 8 + k) * 49 + p];
      *(bf16x8*)dst = o0;
      *(bf16x8*)(dst + 8) = o1;
    }
    return;
  }
  if (blk < 1024) {                       // ---- x convert -> fp8
    size_t i = (size_t)(blk - 512) * 2048 + (size_t)tid * 8;
    f32x4 a = *(const f32x4*)(x + i);
    f32x4 b = *(const f32x4*)(x + i + 4);
    i32x2 o = {pk_fp8x4(a[0], a[1], a[2], a[3]), pk_fp8x4(b[0], b[1], b[2], b[3])};
    *(i32x2*)(xq + i) = o;
    return;
  }
  // ---- gates: one wave per row m
  int wave = tid >> 6, lane = tid & 63;
  int m = (blk - 1024) * 4 + wave;
  const float* trow = te + (size_t)m * S_;
  float acc[E_];
#pragma unroll
  for (int e = 0; e < E_; ++e) acc[e] = 0.f;
  for (int s = lane; s < S_; s += 64) {
    float t = trow[s];
    const f32x4* wgr = (const f32x4*)(Wg + s * E_);
    f32x4 a = wgr[0], b = wgr[1];
    acc[0] += t * a[0]; acc[1] += t * a[1]; acc[2] += t * a[2]; acc[3] += t * a[3];
    acc[4] += t * b[0]; acc[5] += t * b[1]; acc[6] += t * b[2]; acc[7] += t * b[3];
  }
#pragma unroll
  for (int e = 0; e < E_; ++e) {
#pragma unroll
    for (int off = 32; off > 0; off >>= 1) acc[e] += __shfl_xor(acc[e], off, 64);
  }
  if (lane == 0) {
    float lg[E_];
    float m1 = -3.4e38f, m2 = -3.4e38f;
#pragma unroll
    for (int e = 0; e < E_; ++e) {
      float v = acc[e] + bg[e];
      lg[e] = v;
      if (v > m1) { m2 = m1; m1 = v; }
      else if (v > m2) { m2 = v; }
    }
    float den = 0.f, sm[E_];
#pragma unroll
    for (int e = 0; e < E_; ++e) { sm[e] = expf(lg[e] - m1); den += sm[e]; }
    float inv = 1.f / den;
    float dmax = -3.4e38f, dec[E_];
#pragma unroll
    for (int e = 0; e < E_; ++e) {
      float p = sm[e] * inv;
      float d = (lg[e] < m2) ? (10.f * logf(p + 1.f)) : (10.f * (expf(p) - 1.f));
      dec[e] = d;
      dmax = fmaxf(dmax, d);
    }
    float dden = 0.f;
#pragma unroll
    for (int e = 0; e < E_; ++e) { dec[e] = expf(dec[e] - dmax); dden += dec[e]; }
    float dinv = 1.f / dden;
#pragma unroll
    for (int e = 0; e < E_; ++e) gates[m * E_ + e] = dec[e] * dinv;
  }
}

// =================== k_experts: grid (E_, 16, ZSPLIT+1), 512 threads ===================
// GEMM1 in fp8: per kc stage W1q[128h][64k] (8 KB) + Xq[128m][64k] (8 KB) via
// global_load_lds w/ 16B-pair XOR swizzle on the global source col; ds_read_b64
// frags -> mfma_fp8_fp8. gelu (/W1SCALE) -> Hs bf16; GEMM2 bf16 vs direct w2t.
// LDS = 8K + 8K + 34.8K = 51.2 KB -> 3 blocks/CU, 24 waves/CU.
__global__ __launch_bounds__(512, 6) void k_experts(
    const u8* __restrict__ xq,        // [M][S] fp8
    const u8* __restrict__ w1q,       // [E][H][S] fp8 (x W1SCALE)
    const __bf16* __restrict__ w2t,   // [E][P][H] bf16
    const float* __restrict__ b1,     // [E][H]
    const float* __restrict__ b2,     // [E][P]
    const float* __restrict__ gates,  // [M][E]
    float* __restrict__ out)          // [M][P] (+2 loss slots)
{
  __shared__ __align__(16) u8 W1s[BH * BK];          // 8 KB [h][64B], pair-swizzled
  __shared__ __align__(16) u8 Xs[BM * BK];           // 8 KB [m][64B]
  __shared__ __align__(16) __bf16 Hs[BM * HPITCH];   // 34.8 KB -> 51.2 KB total

  const int tid = threadIdx.x;

  if (blockIdx.z == ZSPLIT) {      // ---- loss block (others exit)
    if (blockIdx.x != 0 || blockIdx.y != 0) return;
    float* gsum = (float*)&Hs[0];
    float* cvs  = gsum + F_ * E_;
    float* ents = cvs + F_;
    if (tid < 256) {
      int f = tid >> 3, e = tid & 7;
      float s = 0.f;
      for (int b = 0; b < B_; ++b) s += gates[(size_t)(b * F_ + f) * E_ + e];
      gsum[f * E_ + e] = s;
    }
    __syncthreads();
    if (tid < F_) {
      float mean = 0.f;
#pragma unroll
      for (int k = 0; k < E_; ++k) mean += gsum[tid * E_ + k];
      mean *= (1.f / E_);
      float ss = 0.f;
#pragma unroll
      for (int k = 0; k < E_; ++k) { float d = gsum[tid * E_ + k] - mean; ss += d * d; }
      float var = (float)P_ * ss / (float)(E_ * P_ - 1);
      cvs[tid] = var / (mean * mean + 1e-10f);
      float ent = 0.f;
#pragma unroll
      for (int k = 0; k < E_; ++k) { float g = gsum[tid * E_ + k] * (1.f / B_); ent += -g * logf(g + 1e-8f); }
      ents[tid] = ent * (1.f / E_);
    }
    __syncthreads();
    if (tid == 0) {
      float a = 0.f, b = 0.f;
      for (int k = 0; k < F_; ++k) { a += cvs[k]; b += ents[k]; }
      out[(size_t)M_ * P_ + 0] = a;
      out[(size_t)M_ * P_ + 1] = b;
    }
    return;
  }

  const int wave = tid >> 6, lane = tid & 63;
  const int l15 = lane & 15, quad = lane >> 4;
  const int e = blockIdx.x;
  const int m0 = blockIdx.y * BM;
  const int hz = blockIdx.z * HPZ;

  // staging: 512 threads x 16 B = 8 KB per operand per kc.
  // thread -> (row = tid>>2, 16B-pair = tid&3); source col = (pair ^ (row&3)) * 16.
  const int srow = tid >> 2;
  const int spr = tid & 3;
  const int scol = ((spr ^ (srow & 3)) * 16);
  const u8* xgp = xq + (size_t)(m0 + srow) * S_ + scol;
  const u8* w1gp = w1q + ((size_t)e * H_ + hz + srow) * S_ + scol;
  const __bf16* w2z = w2t + (size_t)e * P_ * H_ + hz;

  // GEMM1 wave tile: 32h x 64m  (8 waves cover 128h x 128m)
  const int hq = (wave & 3) * 32;
  const int mq = (wave >> 2) * 64;
  // GEMM2 wave tile: 32m x 48p
  const int mt = wave & 3;
  const int ph = wave >> 2;

  const f32x4 fz = {0.f, 0.f, 0.f, 0.f};
  f32x4 acc2[2][3];
#pragma unroll
  for (int rt = 0; rt < 2; ++rt)
#pragma unroll
    for (int j = 0; j < 3; ++j) acc2[rt][j] = fz;

  for (int ht = 0; ht < NHT; ++ht) {
    const u8* w1g = w1gp + (size_t)(ht * BH) * S_;
    f32x4 acc1[2][4];
#pragma unroll
    for (int i = 0; i < 2; ++i)
#pragma unroll
      for (int j = 0; j < 4; ++j) acc1[i][j] = fz;

    for (int kc = 0; kc < NKC; ++kc) {
      GLL16(w1g + kc * BK, &W1s[tid * 16]);
      GLL16(xgp + kc * BK, &Xs[tid * 16]);
      __syncthreads();   // vmcnt drain + barrier: staged tiles visible
#pragma unroll
      for (int kk = 0; kk < 2; ++kk) {
        long a[2], b[4];
#pragma unroll
        for (int i = 0; i < 2; ++i) {
          int r = hq + i * 16 + l15;
          int G = kk * 4 + quad;                       // 8B granule index 0..7
          a[i] = *(const long*)&W1s[r * BK + (((G >> 1) ^ (r & 3)) * 16 + (G & 1) * 8)];
        }
#pragma unroll
        for (int j = 0; j < 4; ++j) {
          int r = mq + j * 16 + l15;
          int G = kk * 4 + quad;
          b[j] = *(const long*)&Xs[r * BK + (((G >> 1) ^ (r & 3)) * 16 + (G & 1) * 8)];
        }
#pragma unroll
        for (int i = 0; i < 2; ++i)
#pragma unroll
          for (int j = 0; j < 4; ++j)
            acc1[i][j] = MFMA8(a[i], b[j], acc1[i][j]);
      }
      __syncthreads();   // frag reads done before next stage overwrites
    }

    // bias + gelu (undo W1SCALE) -> Hs[m][h] bf16
    {
      const float* b1w = b1 + (size_t)e * H_ + hz + ht * BH + hq;
#pragma unroll
      for (int i = 0; i < 2; ++i) {
        f32x4 bv = *(const f32x4*)(b1w + i * 16 + quad * 4);
#pragma unroll
        for (int j = 0; j < 4; ++j) {
          bf16x4 hv;
#pragma unroll
          for (int r = 0; r < 4; ++r)
            hv[r] = (__bf16)fast_gelu(acc1[i][j][r] * (1.0f / W1SCALE) + bv[r]);
          *(bf16x4*)&Hs[(mq + j * 16 + l15) * HPITCH + hq + i * 16 + quad * 4] = hv;
        }
      }
    }
    __syncthreads();

    // GEMM2 (bf16): acc2 += Hs[128m x 128h] @ W2chunk[128h x 96p]; B direct from L2-hot w2t
    {
      const __bf16* w2c = w2z + ht * BH;
#pragma unroll
      for (int kk = 0; kk < 4; ++kk) {
        bf16x8 a0 = *(const bf16x8*)&Hs[(mt * 32 + l15) * HPITCH + kk * 32 + quad * 8];
        bf16x8 a1 = *(const bf16x8*)&Hs[(mt * 32 + 16 + l15) * HPITCH + kk * 32 + quad * 8];
#pragma unroll
        for (int j = 0; j < 3; ++j) {
          bf16x8 b = *(const bf16x8*)(w2c + (size_t)(ph * 48 + j * 16 + l15) * H_ + kk * 32 + quad * 8);
          acc2[0][j] = MFMA16(a0, b, acc2[0][j]);
          acc2[1][j] = MFMA16(a1, b, acc2[1][j]);
        }
      }
    }
    // Hs reads (GEMM2) finish before next ht's gelu can rewrite Hs: the entire
    // next k-loop's barriers sit in between. W1s/Xs rewrites are fenced by the
    // k-loop's trailing barrier. Safe.
  }

  // ---- epilogue: out[m,p] += gates[m,e] * (acc + b2 (z==0 only)) ----
#pragma unroll
  for (int rt = 0; rt < 2; ++rt) {
#pragma unroll
    for (int r = 0; r < 4; ++r) {
      int m = m0 + mt * 32 + rt * 16 + quad * 4 + r;
      float g = gates[m * E_ + e];
#pragma unroll
      for (int j = 0; j < 3; ++j) {
        int col = ph * 48 + j * 16 + l15;
        float v = acc2[rt][j][r];
        if (blockIdx.z == 0) v += b2[e * P_ + col];
        atomicAdd(&out[(size_t)m * P_ + col], g * v);
      }
    }
  }
}

extern "C" void kernel_launch(void* const* d_in, const int* in_sizes, int n_in,
                              void* d_out, int out_size, void* d_ws, size_t ws_size,
                              hipStream_t stream) {
  const float* x  = (const float*)d_in[0];
  const float* te = (const float*)d_in[1];
  const float* Wg = (const float*)d_in[2];
  const float* bg = (const float*)d_in[3];
  const float* W1 = (const float*)d_in[4];
  const float* b1 = (const float*)d_in[5];
  const float* W2 = (const float*)d_in[6];
  const float* b2 = (const float*)d_in[7];
  float* out = (float*)d_out;

  char* ws = (char*)d_ws;
  float* gates = (float*)ws;                                 // 65,536 B
  u8* xq       = (u8*)(ws + 65536);                          // 1 MB
  u8* w1q      = (u8*)(ws + 65536 + 1048576);                // 8 MB
  __bf16* w2t  = (__bf16*)(ws + 65536 + 1048576 + 8388608);  // 3 MB

  hipMemsetAsync(d_out, 0, (size_t)out_size * sizeof(float), stream);
  k_prep_w1<<<256, 256, 0, stream>>>(W1, w1q);
  k_prep_rest<<<1536, 256, 0, stream>>>(x, te, Wg, bg, W2, xq, w2t, gates);
  k_experts<<<dim3(E_, M_ / BM, ZSPLIT + 1), 512, 0, stream>>>(xq, w1q, w2t, b1, b2, gates, out);
}

// Round 8
// 194.236 us; speedup vs baseline: 1.2363x; 1.2363x over previous
//
#include <hip/hip_runtime.h>
#include <math.h>

#define B_ 64
#define F_ 32
#define S_ 512
#define P_ 96
#define E_ 8
#define H_ 2048
#define M_ 2048   // B_*F_ rows, m = b*F_ + f

#define BM 128
#define BH 128
#define ZSPLIT 4
#define HPZ (H_ / ZSPLIT)   // 512 h per z-block
#define NHT (HPZ / BH)      // 4 h-chunks per block
#define NKC (S_ / 64)       // 8 k-chunks of 64
#define HPITCH 136          // 128 + 8 skew (bf16)
#define W1SCALE 8.0f
#define TSTRIDE 8192        // bytes per fp8 frag-tile: 64 ksegs x 16 lanes x 8 B

typedef __bf16 bf16x8 __attribute__((ext_vector_type(8)));
typedef __bf16 bf16x4 __attribute__((ext_vector_type(4)));
typedef float f32x4 __attribute__((ext_vector_type(4)));
typedef unsigned char u8;
typedef int i32x2 __attribute__((ext_vector_type(2)));
typedef int i32x4 __attribute__((ext_vector_type(4)));

#define MFMA16(a, b, c) __builtin_amdgcn_mfma_f32_16x16x32_bf16((a), (b), (c), 0, 0, 0)
#define MFMA8(a, b, c) __builtin_amdgcn_mfma_f32_16x16x32_fp8_fp8((a), (b), (c), 0, 0, 0)

__device__ __forceinline__ int pk_fp8x4(float a, float b, float c, float d) {
  int v = __builtin_amdgcn_cvt_pk_fp8_f32(a, b, 0, false);
  return __builtin_amdgcn_cvt_pk_fp8_f32(c, d, v, true);
}

__device__ __forceinline__ float fast_gelu(float x) {
  float e = __builtin_amdgcn_exp2f(-2.45546696f * x);
  return x * __builtin_amdgcn_rcpf(1.0f + e);
}

// =================== k_prep_w1 (256 threads, 256 blocks) ===================
// W1 [E][S][H] f32 -> w1q fp8 in MFMA-frag order: [e][h>>4][s>>3][h&15][8B], x W1SCALE.
// Block = (e, 64-h strip); 2 passes of 256 s.
__global__ __launch_bounds__(256) void k_prep_w1(const float* __restrict__ W1,
                                                 u8* __restrict__ w1q) {
  __shared__ __align__(16) __bf16 btile[256 * 68];   // [s][h] 34,816 B
  const int tid = threadIdx.x;
  const int e = blockIdx.x >> 5, hstrip = blockIdx.x & 31;
  const float* src = W1 + (size_t)e * S_ * H_ + hstrip * 64;
#pragma unroll
  for (int pass = 0; pass < 2; ++pass) {
    {
      int rb = tid >> 2;
      int hseg = (tid & 3) * 16;
#pragma unroll
      for (int it = 0; it < 4; ++it) {
        int r = it * 64 + rb;
        const float* srow = src + (size_t)(pass * 256 + r) * H_ + hseg;
#pragma unroll
        for (int k = 0; k < 4; ++k) {
          f32x4 v = *(const f32x4*)(srow + k * 4);
          bf16x4 o = {(__bf16)v[0], (__bf16)v[1], (__bf16)v[2], (__bf16)v[3]};
          *(bf16x4*)&btile[r * 68 + hseg + k * 4] = o;
        }
      }
    }
    __syncthreads();
    // emit 16-B chunks: (htile-local tloc, kseg gloc, row-pair u)
#pragma unroll
    for (int i = 0; i < 4; ++i) {
      int c = tid + 256 * i;
      int tloc = c >> 8, rem = c & 255;
      int gloc = rem >> 3, u = rem & 7;
      int htile = hstrip * 4 + tloc;
      int g = pass * 32 + gloc;
      float v[16];
#pragma unroll
      for (int rr = 0; rr < 2; ++rr)
#pragma unroll
        for (int j = 0; j < 8; ++j)
          v[rr * 8 + j] = W1SCALE * (float)btile[(gloc * 8 + j) * 68 + tloc * 16 + 2 * u + rr];
      i32x4 o = {pk_fp8x4(v[0], v[1], v[2], v[3]),   pk_fp8x4(v[4], v[5], v[6], v[7]),
                 pk_fp8x4(v[8], v[9], v[10], v[11]), pk_fp8x4(v[12], v[13], v[14], v[15])};
      *(i32x4*)(w1q + ((size_t)(e * 128 + htile) * 64 + g) * 128 + u * 16) = o;
    }
    __syncthreads();
  }
}

// =================== k_prep_rest (256 threads, 1536 blocks) ===================
// [0,512):    W2 [E][H][P] f32 -> w2t [E][P][H] bf16 (64h x 48p tiles)
// [512,1024): x [M][S] f32 -> xq fp8 frag-order [m>>4][s>>3][m&15][8B]
// [1024,1536): gates
__global__ __launch_bounds__(256) void k_prep_rest(const float* __restrict__ x,
                                                   const float* __restrict__ te,
                                                   const float* __restrict__ Wg,
                                                   const float* __restrict__ bg,
                                                   const float* __restrict__ W2,
                                                   u8* __restrict__ xq,
                                                   __bf16* __restrict__ w2t,
                                                   float* __restrict__ gates) {
  __shared__ float tile[64 * 49];
  const int blk = blockIdx.x;
  const int tid = threadIdx.x;

  if (blk < 512) {                        // ---- W2 transpose: tile 64h x 48p
    int e = blk >> 6, hi = (blk >> 1) & 31, ph = blk & 1;
    const float* src = W2 + (size_t)e * H_ * P_ + (size_t)(hi * 64) * P_ + ph * 48;
    {
      int h = tid & 63;
      int seg = tid >> 6;
#pragma unroll
      for (int k = 0; k < 3; ++k) {
        f32x4 v = *(const f32x4*)(src + (size_t)h * P_ + seg * 12 + k * 4);
#pragma unroll
        for (int u = 0; u < 4; ++u) tile[h * 49 + seg * 12 + k * 4 + u] = v[u];
      }
    }
    __syncthreads();
    if (tid < 192) {
      int p = tid >> 2;
      int hb = (tid & 3) * 16;
      __bf16* dst = w2t + (size_t)e * P_ * H_ + (size_t)(ph * 48 + p) * H_ + hi * 64 + hb;
      bf16x8 o0, o1;
#pragma unroll
      for (int k = 0; k < 8; ++k) o0[k] = (__bf16)tile[(hb + k) * 49 + p];
#pragma unroll
      for (int k = 0; k < 8; ++k) o1[k] = (__bf16)tile[(hb + 8 + k) * 49 + p];
      *(bf16x8*)dst = o0;
      *(bf16x8*)(dst + 8) = o1;
    }
    return;
  }
  if (blk < 1024) {                       // ---- x -> fp8 frag-order
    int t = blk - 512;
    int mtile = t >> 2, gq = t & 3;
    int ml = tid & 15, gloc = tid >> 4;   // gloc 0..15
    int g = gq * 16 + gloc;
    const float* srow = x + (size_t)(mtile * 16 + ml) * S_ + g * 8;
    f32x4 a = *(const f32x4*)srow;
    f32x4 b = *(const f32x4*)(srow + 4);
    i32x2 o = {pk_fp8x4(a[0], a[1], a[2], a[3]), pk_fp8x4(b[0], b[1], b[2], b[3])};
    *(i32x2*)(xq + ((size_t)(mtile * 64 + g)) * 128 + ml * 8) = o;
    return;
  }
  // ---- gates: one wave per row m
  int wave = tid >> 6, lane = tid & 63;
  int m = (blk - 1024) * 4 + wave;
  const float* trow = te + (size_t)m * S_;
  float acc[E_];
#pragma unroll
  for (int e = 0; e < E_; ++e) acc[e] = 0.f;
  for (int s = lane; s < S_; s += 64) {
    float t = trow[s];
    const f32x4* wgr = (const f32x4*)(Wg + s * E_);
    f32x4 a = wgr[0], b = wgr[1];
    acc[0] += t * a[0]; acc[1] += t * a[1]; acc[2] += t * a[2]; acc[3] += t * a[3];
    acc[4] += t * b[0]; acc[5] += t * b[1]; acc[6] += t * b[2]; acc[7] += t * b[3];
  }
#pragma unroll
  for (int e = 0; e < E_; ++e) {
#pragma unroll
    for (int off = 32; off > 0; off >>= 1) acc[e] += __shfl_xor(acc[e], off, 64);
  }
  if (lane == 0) {
    float lg[E_];
    float m1 = -3.4e38f, m2 = -3.4e38f;
#pragma unroll
    for (int e = 0; e < E_; ++e) {
      float v = acc[e] + bg[e];
      lg[e] = v;
      if (v > m1) { m2 = m1; m1 = v; }
      else if (v > m2) { m2 = v; }
    }
    float den = 0.f, sm[E_];
#pragma unroll
    for (int e = 0; e < E_; ++e) { sm[e] = expf(lg[e] - m1); den += sm[e]; }
    float inv = 1.f / den;
    float dmax = -3.4e38f, dec[E_];
#pragma unroll
    for (int e = 0; e < E_; ++e) {
      float p = sm[e] * inv;
      float d = (lg[e] < m2) ? (10.f * logf(p + 1.f)) : (10.f * (expf(p) - 1.f));
      dec[e] = d;
      dmax = fmaxf(dmax, d);
    }
    float dden = 0.f;
#pragma unroll
    for (int e = 0; e < E_; ++e) { dec[e] = expf(dec[e] - dmax); dden += dec[e]; }
    float dinv = 1.f / dden;
#pragma unroll
    for (int e = 0; e < E_; ++e) gates[m * E_ + e] = dec[e] * dinv;
  }
}

// =================== k_experts: grid (E_, 16, ZSPLIT+1), 512 threads ===================
// GEMM1: barrier-free, LDS-free — A (w1q) and B (xq) frags loaded directly from
// global in MFMA-frag order (each wave load = 512 contiguous bytes). fp8 MFMA.
// gelu -> Hs (only LDS, 34.8 KB -> 2 blocks/CU uniform); GEMM2 bf16 vs direct w2t.
// 2 barriers per ht (8 per block) instead of 64.
__global__ __launch_bounds__(512, 4) void k_experts(
    const u8* __restrict__ xq,        // fp8 frag-order [m>>4][s>>3][m&15][8]
    const u8* __restrict__ w1q,       // fp8 frag-order [e][h>>4][s>>3][h&15][8], x W1SCALE
    const __bf16* __restrict__ w2t,   // [E][P][H] bf16
    const float* __restrict__ b1,     // [E][H]
    const float* __restrict__ b2,     // [E][P]
    const float* __restrict__ gates,  // [M][E]
    float* __restrict__ out)          // [M][P] (+2 loss slots)
{
  __shared__ __align__(16) __bf16 Hs[BM * HPITCH];   // 34.8 KB

  const int tid = threadIdx.x;

  if (blockIdx.z == ZSPLIT) {      // ---- loss block (others exit)
    if (blockIdx.x != 0 || blockIdx.y != 0) return;
    float* gsum = (float*)&Hs[0];
    float* cvs  = gsum + F_ * E_;
    float* ents = cvs + F_;
    if (tid < 256) {
      int f = tid >> 3, e = tid & 7;
      float s = 0.f;
      for (int b = 0; b < B_; ++b) s += gates[(size_t)(b * F_ + f) * E_ + e];
      gsum[f * E_ + e] = s;
    }
    __syncthreads();
    if (tid < F_) {
      float mean = 0.f;
#pragma unroll
      for (int k = 0; k < E_; ++k) mean += gsum[tid * E_ + k];
      mean *= (1.f / E_);
      float ss = 0.f;
#pragma unroll
      for (int k = 0; k < E_; ++k) { float d = gsum[tid * E_ + k] - mean; ss += d * d; }
      float var = (float)P_ * ss / (float)(E_ * P_ - 1);
      cvs[tid] = var / (mean * mean + 1e-10f);
      float ent = 0.f;
#pragma unroll
      for (int k = 0; k < E_; ++k) { float g = gsum[tid * E_ + k] * (1.f / B_); ent += -g * logf(g + 1e-8f); }
      ents[tid] = ent * (1.f / E_);
    }
    __syncthreads();
    if (tid == 0) {
      float a = 0.f, b = 0.f;
      for (int k = 0; k < F_; ++k) { a += cvs[k]; b += ents[k]; }
      out[(size_t)M_ * P_ + 0] = a;
      out[(size_t)M_ * P_ + 1] = b;
    }
    return;
  }

  const int wave = tid >> 6, lane = tid & 63;
  const int l15 = lane & 15, quad = lane >> 4;
  const int e = blockIdx.x;
  const int m0 = blockIdx.y * BM;
  const int hz = blockIdx.z * HPZ;

  // GEMM1 wave tile: 32h x 64m; GEMM2 wave tile: 32m x 48p
  const int hq = (wave & 3) * 32;
  const int mq = (wave >> 2) * 64;
  const int mt = wave & 3;
  const int ph = wave >> 2;

  // frag-order base pointers (quad -> kseg offset, l15 -> lane row)
  const u8* w1b = w1q + (size_t)(e * 128 + (hz >> 4) + (hq >> 4)) * TSTRIDE + quad * 128 + l15 * 8;
  const u8* xb  = xq  + (size_t)((m0 >> 4) + (mq >> 4)) * TSTRIDE + quad * 128 + l15 * 8;
  const __bf16* w2z = w2t + (size_t)e * P_ * H_ + hz;

  const f32x4 fz = {0.f, 0.f, 0.f, 0.f};
  f32x4 acc2[2][3];
#pragma unroll
  for (int rt = 0; rt < 2; ++rt)
#pragma unroll
    for (int j = 0; j < 3; ++j) acc2[rt][j] = fz;

  for (int ht = 0; ht < NHT; ++ht) {
    const u8* w1h = w1b + (size_t)(ht * 8) * TSTRIDE;
    f32x4 acc1[2][4];
#pragma unroll
    for (int i = 0; i < 2; ++i)
#pragma unroll
      for (int j = 0; j < 4; ++j) acc1[i][j] = fz;

    // barrier-free K loop: 12 dwordx2 loads + 16 MFMA per kc; compiler pipelines
#pragma unroll 2
    for (int kc = 0; kc < NKC; ++kc) {
      long a[2][2], b[2][4];
#pragma unroll
      for (int kk = 0; kk < 2; ++kk) {
        int ko = (kc * 8 + kk * 4) * 128;
#pragma unroll
        for (int i = 0; i < 2; ++i)
          a[kk][i] = *(const long*)(w1h + (size_t)i * TSTRIDE + ko);
#pragma unroll
        for (int j = 0; j < 4; ++j)
          b[kk][j] = *(const long*)(xb + (size_t)j * TSTRIDE + ko);
      }
#pragma unroll
      for (int kk = 0; kk < 2; ++kk)
#pragma unroll
        for (int i = 0; i < 2; ++i)
#pragma unroll
          for (int j = 0; j < 4; ++j)
            acc1[i][j] = MFMA8(a[kk][i], b[kk][j], acc1[i][j]);
    }

    // bias + gelu (undo W1SCALE) -> Hs[m][h] bf16
    {
      const float* b1w = b1 + (size_t)e * H_ + hz + ht * BH + hq;
#pragma unroll
      for (int i = 0; i < 2; ++i) {
        f32x4 bv = *(const f32x4*)(b1w + i * 16 + quad * 4);
#pragma unroll
        for (int j = 0; j < 4; ++j) {
          bf16x4 hv;
#pragma unroll
          for (int r = 0; r < 4; ++r)
            hv[r] = (__bf16)fast_gelu(acc1[i][j][r] * (1.0f / W1SCALE) + bv[r]);
          *(bf16x4*)&Hs[(mq + j * 16 + l15) * HPITCH + hq + i * 16 + quad * 4] = hv;
        }
      }
    }
    __syncthreads();

    // GEMM2 (bf16): acc2 += Hs[128m x 128h] @ W2chunk[128h x 96p]
    {
      const __bf16* w2c = w2z + ht * BH;
#pragma unroll
      for (int kk = 0; kk < 4; ++kk) {
        bf16x8 a0 = *(const bf16x8*)&Hs[(mt * 32 + l15) * HPITCH + kk * 32 + quad * 8];
        bf16x8 a1 = *(const bf16x8*)&Hs[(mt * 32 + 16 + l15) * HPITCH + kk * 32 + quad * 8];
#pragma unroll
        for (int j = 0; j < 3; ++j) {
          bf16x8 b = *(const bf16x8*)(w2c + (size_t)(ph * 48 + j * 16 + l15) * H_ + kk * 32 + quad * 8);
          acc2[0][j] = MFMA16(a0, b, acc2[0][j]);
          acc2[1][j] = MFMA16(a1, b, acc2[1][j]);
        }
      }
    }
    __syncthreads();   // Hs reads done before next ht's gelu rewrites
  }

  // ---- epilogue: out[m,p] += gates[m,e] * (acc + b2 (z==0 only)) ----
#pragma unroll
  for (int rt = 0; rt < 2; ++rt) {
#pragma unroll
    for (int r = 0; r < 4; ++r) {
      int m = m0 + mt * 32 + rt * 16 + quad * 4 + r;
      float g = gates[m * E_ + e];
#pragma unroll
      for (int j = 0; j < 3; ++j) {
        int col = ph * 48 + j * 16 + l15;
        float v = acc2[rt][j][r];
        if (blockIdx.z == 0) v += b2[e * P_ + col];
        atomicAdd(&out[(size_t)m * P_ + col], g * v);
      }
    }
  }
}

extern "C" void kernel_launch(void* const* d_in, const int* in_sizes, int n_in,
                              void* d_out, int out_size, void* d_ws, size_t ws_size,
                              hipStream_t stream) {
  const float* x  = (const float*)d_in[0];
  const float* te = (const float*)d_in[1];
  const float* Wg = (const float*)d_in[2];
  const float* bg = (const float*)d_in[3];
  const float* W1 = (const float*)d_in[4];
  const float* b1 = (const float*)d_in[5];
  const float* W2 = (const float*)d_in[6];
  const float* b2 = (const float*)d_in[7];
  float* out = (float*)d_out;

  char* ws = (char*)d_ws;
  float* gates = (float*)ws;                                 // 65,536 B
  u8* xq       = (u8*)(ws + 65536);                          // 1 MB
  u8* w1q      = (u8*)(ws + 65536 + 1048576);                // 8 MB
  __bf16* w2t  = (__bf16*)(ws + 65536 + 1048576 + 8388608);  // 3 MB

  hipMemsetAsync(d_out, 0, (size_t)out_size * sizeof(float), stream);
  k_prep_w1<<<256, 256, 0, stream>>>(W1, w1q);
  k_prep_rest<<<1536, 256, 0, stream>>>(x, te, Wg, bg, W2, xq, w2t, gates);
  k_experts<<<dim3(E_, M_ / BM, ZSPLIT + 1), 512, 0, stream>>>(xq, w1q, w2t, b1, b2, gates, out);
}